// Round 3
// baseline (1008.173 us; speedup 1.0000x reference)
//
#include <hip/hip_runtime.h>
#include <stdint.h>

#define NEG_SLOPE 0.2f
#define BN_EPS 1e-5f

// ---------------- bf16 helpers ----------------
__device__ __forceinline__ float bf2f(unsigned short u) {
  union { unsigned int i; float f; } v; v.i = ((unsigned int)u) << 16; return v.f;
}
__device__ __forceinline__ unsigned short f2bf(float f) {
  union { float f; unsigned int i; } v; v.f = f;
  unsigned int i = v.i;
  return (unsigned short)((i + 0x7fffu + ((i >> 16) & 1u)) >> 16);  // RNE
}
// flexible float load: f32 ? fp32 : bf16
__device__ __forceinline__ float loadF(const void* p, long long i, int f32) {
  return f32 ? ((const float*)p)[i] : bf2f(((const unsigned short*)p)[i]);
}
__device__ __forceinline__ int edge_at(const void* ei, long long idx, int is64) {
  return is64 ? (int)((const long long*)ei)[idx] : ((const int*)ei)[idx];
}

// ---------------- input dtype detection ----------------
// flags[0] = 1 if float inputs are fp32 (not bf16); flags[1] = 1 if edge_index is int64
__global__ void detect_kernel(const unsigned short* __restrict__ x,
                              const int* __restrict__ ei32,
                              int* __restrict__ flags) {
  __shared__ int wild, oddnz;
  if (threadIdx.x == 0) { wild = 0; oddnz = 0; }
  __syncthreads();
  int lw = 0, lo = 0;
  for (int i = threadIdx.x; i < 4096; i += 256) {
    unsigned short u = x[i];
    int ex = (u >> 7) & 0xFF;          // bf16 exponent field
    if (ex >= 0x86) lw++;              // |v| >= 128 or inf/nan: impossible for N(0,1) bf16
    if (ei32[2 * i + 1] != 0) lo++;    // int64 values < 2^31 -> high words all zero
  }
  if (lw) atomicAdd(&wild, lw);
  if (lo) atomicAdd(&oddnz, lo);
  __syncthreads();
  if (threadIdx.x == 0) { flags[0] = (wild > 64) ? 1 : 0; flags[1] = (oddnz == 0) ? 1 : 0; }
}

// ---------------- CSR build ----------------
__global__ __launch_bounds__(256) void hist_kernel(const void* __restrict__ ei, int E, int N,
                                                   const int* __restrict__ flags,
                                                   int* __restrict__ deg) {
  int e = blockIdx.x * 256 + threadIdx.x;
  if (e >= E) return;
  int is64 = flags[1];
  int d = edge_at(ei, (long long)E + e, is64);
  d = (d < 0 || d >= N) ? 0 : d;
  atomicAdd(&deg[d], 1);
}

// single wave exclusive scan: offsets[0]=0, offsets[i+1]=offsets[i]+deg[i]
__global__ void scan_kernel(const int* __restrict__ deg, int* __restrict__ offsets, int N) {
  int lane = threadIdx.x;  // 64 threads
  int base = 0;
  if (lane == 0) offsets[0] = 0;
  for (int start = 0; start < N; start += 64) {
    int idx = start + lane;
    int v = (idx < N) ? deg[idx] : 0;
    int sc = v;
    #pragma unroll
    for (int o = 1; o < 64; o <<= 1) {
      int u = __shfl_up(sc, o);
      if (lane >= o) sc += u;
    }
    if (idx < N) offsets[idx + 1] = base + sc;
    base = __shfl(base + sc, 63);
  }
}

__global__ __launch_bounds__(256) void scatter_kernel(
    const void* __restrict__ ei, int E, int N, const int* __restrict__ flags,
    const int* __restrict__ offsets, int* __restrict__ cursor,
    int* __restrict__ csr_src) {
  int e = blockIdx.x * 256 + threadIdx.x;
  if (e >= E) return;
  int is64 = flags[1];
  int s = edge_at(ei, e, is64);
  int d = edge_at(ei, (long long)E + e, is64);
  s = (s < 0 || s >= N) ? 0 : s;
  d = (d < 0 || d >= N) ? 0 : d;
  int pos = offsets[d] + atomicAdd(&cursor[d], 1);
  csr_src[pos] = s;
}

// ---------------- xh = x @ W  + attention logits ----------------
// x [N,64], W [64,256] -> xh bf16 [N,256], als/ald fp32 [N,4]
// x_flex: 1 -> x dtype follows flags[0]; 0 -> x is always bf16 (internal buffer)
__global__ __launch_bounds__(256) void gemm_al_kernel(
    const void* __restrict__ x, const void* __restrict__ W,
    const void* __restrict__ a_src, const void* __restrict__ a_dst,
    const int* __restrict__ flags, int x_flex,
    unsigned short* __restrict__ xh, float* __restrict__ als, float* __restrict__ ald,
    int N) {
  __shared__ unsigned short Ws[64 * 256];
  int f32 = flags[0];
  int xf = x_flex ? f32 : 0;
  int t = threadIdx.x;
  for (int i = t; i < 64 * 256; i += 256)
    Ws[i] = f32 ? f2bf(((const float*)W)[i]) : ((const unsigned short*)W)[i];
  __syncthreads();
  int lane = t & 63;
  int wid = t >> 6;
  int h = lane >> 4;                     // head for this lane's 4 channels
  float as0 = loadF(a_src, 4 * lane + 0, f32), as1 = loadF(a_src, 4 * lane + 1, f32);
  float as2 = loadF(a_src, 4 * lane + 2, f32), as3 = loadF(a_src, 4 * lane + 3, f32);
  float ad0 = loadF(a_dst, 4 * lane + 0, f32), ad1 = loadF(a_dst, 4 * lane + 1, f32);
  float ad2 = loadF(a_dst, 4 * lane + 2, f32), ad3 = loadF(a_dst, 4 * lane + 3, f32);
  const ushort4* Wsv = (const ushort4*)Ws;
  int nw = gridDim.x * 4;
  for (int n = blockIdx.x * 4 + wid; n < N; n += nw) {
    float xv = loadF(x, (long long)n * 64 + lane, xf);
    float a0 = 0.f, a1 = 0.f, a2 = 0.f, a3 = 0.f;
    #pragma unroll 8
    for (int k = 0; k < 64; k++) {
      float xk = __shfl(xv, k);
      ushort4 w4 = Wsv[k * 64 + lane];   // bank = 2*lane % 32: 2-way (free)
      a0 += xk * bf2f(w4.x);
      a1 += xk * bf2f(w4.y);
      a2 += xk * bf2f(w4.z);
      a3 += xk * bf2f(w4.w);
    }
    ushort4 o; o.x = f2bf(a0); o.y = f2bf(a1); o.z = f2bf(a2); o.w = f2bf(a3);
    ((ushort4*)xh)[(long long)n * 64 + lane] = o;
    float ps = a0 * as0 + a1 * as1 + a2 * as2 + a3 * as3;
    float pd = a0 * ad0 + a1 * ad1 + a2 * ad2 + a3 * ad3;
    #pragma unroll
    for (int ofs = 1; ofs < 16; ofs <<= 1) {  // reduce within 16-lane head group
      ps += __shfl_xor(ps, ofs);
      pd += __shfl_xor(pd, ofs);
    }
    if ((lane & 15) == 0) { als[n * 4 + h] = ps; ald[n * 4 + h] = pd; }
  }
}

// ---------------- per-dst-node softmax aggregation ----------------
// one wave per node; lane l -> flat channels 4l..4l+3 (head l>>4).
// y fp32 [N,64]; saved (optional) fp32 [N,64]
__global__ __launch_bounds__(256) void agg_kernel(
    const unsigned short* __restrict__ xh,
    const float* __restrict__ als, const float* __restrict__ ald,
    const int* __restrict__ offsets, const int* __restrict__ csr_src,
    const void* __restrict__ bias, const int* __restrict__ flags,
    float* __restrict__ y, float* __restrict__ saved, int N) {
  int lane = threadIdx.x & 63;
  int wid = threadIdx.x >> 6;
  int n = blockIdx.x * 4 + wid;
  if (n >= N) return;
  int h = lane >> 4;
  float ad = ald[n * 4 + h];
  // implicit self loop (PyG add_self_loops)
  float e = als[n * 4 + h] + ad;
  e = (e > 0.f) ? e : NEG_SLOPE * e;
  e = fminf(fmaxf(e, -60.f), 60.f);          // safety clamp (no-op for sane data)
  float p = __expf(e);
  float dsum = p;
  ushort4 x4 = ((const ushort4*)xh)[(long long)n * 64 + lane];
  float a0 = p * bf2f(x4.x), a1 = p * bf2f(x4.y), a2 = p * bf2f(x4.z), a3 = p * bf2f(x4.w);
  int beg = offsets[n], end = offsets[n + 1];
  for (int j = beg; j < end; j++) {
    int s = csr_src[j];
    s = (s < 0 || s >= N) ? 0 : s;           // safety clamp
    float e2 = als[s * 4 + h] + ad;
    e2 = (e2 > 0.f) ? e2 : NEG_SLOPE * e2;
    e2 = fminf(fmaxf(e2, -60.f), 60.f);
    float p2 = __expf(e2);
    dsum += p2;
    ushort4 v = ((const ushort4*)xh)[(long long)s * 64 + lane];
    a0 += p2 * bf2f(v.x);
    a1 += p2 * bf2f(v.y);
    a2 += p2 * bf2f(v.z);
    a3 += p2 * bf2f(v.w);
  }
  float inv = 1.0f / fmaxf(dsum, 1e-30f);
  a0 *= inv; a1 *= inv; a2 *= inv; a3 *= inv;
  // mean over 4 heads: flat channel c lives in lanes {c>>2, +16h}
  a0 += __shfl_xor(a0, 16); a0 += __shfl_xor(a0, 32);
  a1 += __shfl_xor(a1, 16); a1 += __shfl_xor(a1, 32);
  a2 += __shfl_xor(a2, 16); a2 += __shfl_xor(a2, 32);
  a3 += __shfl_xor(a3, 16); a3 += __shfl_xor(a3, 32);
  if (lane < 16) {
    int f32 = flags[0];
    float4 o;
    o.x = 0.25f * a0 + loadF(bias, 4 * lane + 0, f32);
    o.y = 0.25f * a1 + loadF(bias, 4 * lane + 1, f32);
    o.z = 0.25f * a2 + loadF(bias, 4 * lane + 2, f32);
    o.w = 0.25f * a3 + loadF(bias, 4 * lane + 3, f32);
    ((float4*)(y + (size_t)n * 64))[lane] = o;
    if (saved) ((float4*)(saved + (size_t)n * 64))[lane] = o;  // fp32 output
  }
}

// ---------------- BN stats (per-channel sum / sumsq) ----------------
__global__ __launch_bounds__(256) void stats_kernel(const float* __restrict__ y,
                                                    float* __restrict__ gsum,
                                                    float* __restrict__ gsq, int N) {
  __shared__ float ls[256], lq[256];
  int t = threadIdx.x;
  int c = t & 63;
  int r0 = blockIdx.x * 4 + (t >> 6);
  float s = 0.f, q = 0.f;
  for (int r = r0; r < N; r += gridDim.x * 4) {
    float v = y[(size_t)r * 64 + c];
    s += v; q += v * v;
  }
  ls[t] = s; lq[t] = q;
  __syncthreads();
  if (t < 64) {
    s = ls[t] + ls[t + 64] + ls[t + 128] + ls[t + 192];
    q = lq[t] + lq[t + 64] + lq[t + 128] + lq[t + 192];
    atomicAdd(&gsum[c], s);
    atomicAdd(&gsq[c], q);
  }
}

// ---------------- BN apply + ReLU ----------------
// out_f (fp32, optional) and/or out_b (bf16, optional)
__global__ __launch_bounds__(256) void bn_kernel(
    const float* __restrict__ y, const float* __restrict__ gsum, const float* __restrict__ gsq,
    const void* __restrict__ gamma, const void* __restrict__ beta,
    const int* __restrict__ flags, float* __restrict__ out_f,
    unsigned short* __restrict__ out_b, int N) {
  int i = blockIdx.x * 256 + threadIdx.x;  // one float4 (4 channels) per thread
  if (i >= N * 16) return;
  int f32 = flags[0];
  int cg = i & 15;
  float4 v = ((const float4*)y)[i];
  float4 s = ((const float4*)gsum)[cg];
  float4 q = ((const float4*)gsq)[cg];
  float inv_n = 1.0f / (float)N;
  float vv[4] = {v.x, v.y, v.z, v.w};
  float ss[4] = {s.x, s.y, s.z, s.w};
  float qq[4] = {q.x, q.y, q.z, q.w};
  float o[4];
  #pragma unroll
  for (int k = 0; k < 4; k++) {
    float g = loadF(gamma, 4 * cg + k, f32);
    float b = loadF(beta, 4 * cg + k, f32);
    float mu = ss[k] * inv_n;
    float var = fmaxf(qq[k] * inv_n - mu * mu, 0.f);
    float r = g * (vv[k] - mu) * rsqrtf(var + BN_EPS) + b;
    o[k] = r > 0.f ? r : 0.f;
  }
  if (out_f) {
    float4 ov; ov.x = o[0]; ov.y = o[1]; ov.z = o[2]; ov.w = o[3];
    ((float4*)out_f)[i] = ov;
  }
  if (out_b) {
    ushort4 ov;
    ov.x = f2bf(o[0]); ov.y = f2bf(o[1]); ov.z = f2bf(o[2]); ov.w = f2bf(o[3]);
    ((ushort4*)out_b)[i] = ov;
  }
}

// ---------------- launch ----------------
extern "C" void kernel_launch(void* const* d_in, const int* in_sizes, int n_in,
                              void* d_out, int out_size, void* d_ws, size_t ws_size,
                              hipStream_t stream) {
  const void* x    = d_in[0];
  const void* ei   = d_in[1];
  // d_in[2] edge_weight: ignored (edge_dim=None in reference)
  const void* W0    = d_in[3];
  const void* asrc0 = d_in[4];
  const void* adst0 = d_in[5];
  const void* b0    = d_in[6];
  const void* g0    = d_in[7];
  const void* be0   = d_in[8];
  const void* W1    = d_in[9];
  const void* asrc1 = d_in[10];
  const void* adst1 = d_in[11];
  const void* b1    = d_in[12];
  const void* g1    = d_in[13];
  const void* be1   = d_in[14];

  int N = in_sizes[0] / 64;
  int E = in_sizes[1] / 2;

  // workspace carve (256B aligned chunks)
  char* p = (char*)d_ws;
  auto alloc = [&](size_t bytes) -> char* {
    char* r = p;
    p += (bytes + 255) & ~(size_t)255;
    return r;
  };
  int* flags    = (int*)alloc(256);
  int* deg      = (int*)alloc((size_t)N * 4);
  int* cursor   = (int*)alloc((size_t)N * 4);
  int* offsets  = (int*)alloc((size_t)(N + 1) * 4);
  int* csr_src  = (int*)alloc((size_t)E * 4);
  unsigned short* xh = (unsigned short*)alloc((size_t)N * 256 * 2);
  float* als    = (float*)alloc((size_t)N * 4 * 4);
  float* ald    = (float*)alloc((size_t)N * 4 * 4);
  float* y      = (float*)alloc((size_t)N * 64 * 4);
  unsigned short* x2 = (unsigned short*)alloc((size_t)N * 64 * 2);
  float* gsum0  = (float*)alloc(256);
  float* gsq0   = (float*)alloc(256);
  float* gsum1  = (float*)alloc(256);
  float* gsq1   = (float*)alloc(256);

  hipMemsetAsync(deg, 0, (size_t)N * 4, stream);
  hipMemsetAsync(cursor, 0, (size_t)N * 4, stream);
  hipMemsetAsync(gsum0, 0, 1024, stream);  // gsum0..gsq1 contiguous 4x256B

  detect_kernel<<<1, 256, 0, stream>>>((const unsigned short*)x, (const int*)ei, flags);

  // CSR build (shared by both layers)
  hist_kernel<<<(E + 255) / 256, 256, 0, stream>>>(ei, E, N, flags, deg);
  scan_kernel<<<1, 64, 0, stream>>>(deg, offsets, N);
  scatter_kernel<<<(E + 255) / 256, 256, 0, stream>>>(ei, E, N, flags, offsets, cursor, csr_src);

  float* out_x = (float*)d_out;                    // output 0: final (post BN+ReLU), fp32
  float* out_saved = out_x + (size_t)N * 64;       // output 1: layer-2 pre-BN, fp32

  // ---- layer 0 ----
  gemm_al_kernel<<<512, 256, 0, stream>>>(x, W0, asrc0, adst0, flags, 1, xh, als, ald, N);
  agg_kernel<<<(N + 3) / 4, 256, 0, stream>>>(xh, als, ald, offsets, csr_src, b0, flags, y,
                                              (float*)nullptr, N);
  stats_kernel<<<120, 256, 0, stream>>>(y, gsum0, gsq0, N);
  bn_kernel<<<(N * 16 + 255) / 256, 256, 0, stream>>>(y, gsum0, gsq0, g0, be0, flags,
                                                      (float*)nullptr, x2, N);

  // ---- layer 1 ----
  gemm_al_kernel<<<512, 256, 0, stream>>>(x2, W1, asrc1, adst1, flags, 0, xh, als, ald, N);
  agg_kernel<<<(N + 3) / 4, 256, 0, stream>>>(xh, als, ald, offsets, csr_src, b1, flags, y,
                                              out_saved, N);
  stats_kernel<<<120, 256, 0, stream>>>(y, gsum1, gsq1, N);
  bn_kernel<<<(N * 16 + 255) / 256, 256, 0, stream>>>(y, gsum1, gsq1, g1, be1, flags,
                                                      out_x, (unsigned short*)nullptr, N);
}

// Round 4
// 651.228 us; speedup vs baseline: 1.5481x; 1.5481x over previous
//
#include <hip/hip_runtime.h>
#include <stdint.h>

#define NEG_SLOPE 0.2f
#define BN_EPS 1e-5f

// ---------------- bf16 helpers ----------------
__device__ __forceinline__ float bf2f(unsigned short u) {
  union { unsigned int i; float f; } v; v.i = ((unsigned int)u) << 16; return v.f;
}
__device__ __forceinline__ unsigned short f2bf(float f) {
  union { float f; unsigned int i; } v; v.f = f;
  unsigned int i = v.i;
  return (unsigned short)((i + 0x7fffu + ((i >> 16) & 1u)) >> 16);  // RNE
}
// flexible float load: f32 ? fp32 : bf16
__device__ __forceinline__ float loadF(const void* p, long long i, int f32) {
  return f32 ? ((const float*)p)[i] : bf2f(((const unsigned short*)p)[i]);
}
__device__ __forceinline__ int edge_at(const void* ei, long long idx, int is64) {
  return is64 ? (int)((const long long*)ei)[idx] : ((const int*)ei)[idx];
}

// ---------------- input dtype detection ----------------
// flags[0] = 1 if float inputs are fp32 (not bf16); flags[1] = 1 if edge_index is int64
__global__ void detect_kernel(const unsigned short* __restrict__ x,
                              const int* __restrict__ ei32,
                              int* __restrict__ flags) {
  __shared__ int wild, oddnz;
  if (threadIdx.x == 0) { wild = 0; oddnz = 0; }
  __syncthreads();
  int lw = 0, lo = 0;
  for (int i = threadIdx.x; i < 4096; i += 256) {
    unsigned short u = x[i];
    int ex = (u >> 7) & 0xFF;          // bf16 exponent field
    if (ex >= 0x86) lw++;              // |v| >= 128 or inf/nan: impossible for N(0,1) bf16
    if (ei32[2 * i + 1] != 0) lo++;    // int64 values < 2^31 -> high words all zero
  }
  if (lw) atomicAdd(&wild, lw);
  if (lo) atomicAdd(&oddnz, lo);
  __syncthreads();
  if (threadIdx.x == 0) { flags[0] = (wild > 64) ? 1 : 0; flags[1] = (oddnz == 0) ? 1 : 0; }
}

// ---------------- CSR build ----------------
__global__ __launch_bounds__(256) void hist_kernel(const void* __restrict__ ei, int E, int N,
                                                   const int* __restrict__ flags,
                                                   int* __restrict__ deg) {
  int e = blockIdx.x * 256 + threadIdx.x;
  if (e >= E) return;
  int is64 = flags[1];
  int d = edge_at(ei, (long long)E + e, is64);
  d = (d < 0 || d >= N) ? 0 : d;
  atomicAdd(&deg[d], 1);
}

// ---- hierarchical scan: 3 kernels, all parallel ----
// 1) per-block (256-elem chunk) sums
__global__ __launch_bounds__(256) void partial_kernel(const int* __restrict__ deg,
                                                      int* __restrict__ blocksum, int N) {
  int t = threadIdx.x;
  int idx = blockIdx.x * 256 + t;
  int v = (idx < N) ? deg[idx] : 0;
  // wave reduce
  #pragma unroll
  for (int o = 1; o < 64; o <<= 1) v += __shfl_xor(v, o);
  __shared__ int ws[4];
  if ((t & 63) == 0) ws[t >> 6] = v;
  __syncthreads();
  if (t == 0) blocksum[blockIdx.x] = ws[0] + ws[1] + ws[2] + ws[3];
}

// 2) single-wave exclusive scan of block sums (B <= a few hundred)
__global__ void scan_base_kernel(const int* __restrict__ blocksum,
                                 int* __restrict__ blockbase, int B) {
  int lane = threadIdx.x;  // 64 threads
  int base = 0;
  if (lane == 0) blockbase[0] = 0;
  for (int start = 0; start < B; start += 64) {
    int idx = start + lane;
    int v = (idx < B) ? blocksum[idx] : 0;
    int sc = v;
    #pragma unroll
    for (int o = 1; o < 64; o <<= 1) {
      int u = __shfl_up(sc, o);
      if (lane >= o) sc += u;
    }
    if (idx < B) blockbase[idx + 1] = base + sc;
    base = __shfl(base + sc, 63);
  }
}

// 3) per-block inclusive scan + base -> offsets[idx+1]; offsets[0]=0
__global__ __launch_bounds__(256) void scan_final_kernel(const int* __restrict__ deg,
                                                         const int* __restrict__ blockbase,
                                                         int* __restrict__ offsets, int N) {
  int t = threadIdx.x;
  int lane = t & 63;
  int wid = t >> 6;
  int idx = blockIdx.x * 256 + t;
  int v = (idx < N) ? deg[idx] : 0;
  int sc = v;
  #pragma unroll
  for (int o = 1; o < 64; o <<= 1) {
    int u = __shfl_up(sc, o);
    if (lane >= o) sc += u;
  }
  __shared__ int ws[4];
  if (lane == 63) ws[wid] = sc;
  __syncthreads();
  int add = 0;
  #pragma unroll
  for (int w = 0; w < 4; w++) if (w < wid) add += ws[w];
  if (idx < N) offsets[idx + 1] = blockbase[blockIdx.x] + add + sc;
  if (idx == 0) offsets[0] = 0;
}

__global__ __launch_bounds__(256) void scatter_kernel(
    const void* __restrict__ ei, int E, int N, const int* __restrict__ flags,
    const int* __restrict__ offsets, int* __restrict__ cursor,
    int* __restrict__ csr_src) {
  int e = blockIdx.x * 256 + threadIdx.x;
  if (e >= E) return;
  int is64 = flags[1];
  int s = edge_at(ei, e, is64);
  int d = edge_at(ei, (long long)E + e, is64);
  s = (s < 0 || s >= N) ? 0 : s;
  d = (d < 0 || d >= N) ? 0 : d;
  int pos = offsets[d] + atomicAdd(&cursor[d], 1);
  csr_src[pos] = s;
}

// ---------------- xh = x @ W  + attention logits ----------------
// x [N,64], W [64,256] -> xh bf16 [N,256], als/ald fp32 [N,4]
// x_flex: 1 -> x dtype follows flags[0]; 0 -> x is always bf16 (internal buffer)
__global__ __launch_bounds__(256) void gemm_al_kernel(
    const void* __restrict__ x, const void* __restrict__ W,
    const void* __restrict__ a_src, const void* __restrict__ a_dst,
    const int* __restrict__ flags, int x_flex,
    unsigned short* __restrict__ xh, float* __restrict__ als, float* __restrict__ ald,
    int N) {
  __shared__ unsigned short Ws[64 * 256];
  int f32 = flags[0];
  int xf = x_flex ? f32 : 0;
  int t = threadIdx.x;
  for (int i = t; i < 64 * 256; i += 256)
    Ws[i] = f32 ? f2bf(((const float*)W)[i]) : ((const unsigned short*)W)[i];
  __syncthreads();
  int lane = t & 63;
  int wid = t >> 6;
  int h = lane >> 4;                     // head for this lane's 4 channels
  float as0 = loadF(a_src, 4 * lane + 0, f32), as1 = loadF(a_src, 4 * lane + 1, f32);
  float as2 = loadF(a_src, 4 * lane + 2, f32), as3 = loadF(a_src, 4 * lane + 3, f32);
  float ad0 = loadF(a_dst, 4 * lane + 0, f32), ad1 = loadF(a_dst, 4 * lane + 1, f32);
  float ad2 = loadF(a_dst, 4 * lane + 2, f32), ad3 = loadF(a_dst, 4 * lane + 3, f32);
  const ushort4* Wsv = (const ushort4*)Ws;
  int nw = gridDim.x * 4;
  for (int n = blockIdx.x * 4 + wid; n < N; n += nw) {
    float xv = loadF(x, (long long)n * 64 + lane, xf);
    float a0 = 0.f, a1 = 0.f, a2 = 0.f, a3 = 0.f;
    #pragma unroll 8
    for (int k = 0; k < 64; k++) {
      float xk = __shfl(xv, k);
      ushort4 w4 = Wsv[k * 64 + lane];   // bank = 2*lane % 32: 2-way (free)
      a0 += xk * bf2f(w4.x);
      a1 += xk * bf2f(w4.y);
      a2 += xk * bf2f(w4.z);
      a3 += xk * bf2f(w4.w);
    }
    ushort4 o; o.x = f2bf(a0); o.y = f2bf(a1); o.z = f2bf(a2); o.w = f2bf(a3);
    ((ushort4*)xh)[(long long)n * 64 + lane] = o;
    float ps = a0 * as0 + a1 * as1 + a2 * as2 + a3 * as3;
    float pd = a0 * ad0 + a1 * ad1 + a2 * ad2 + a3 * ad3;
    #pragma unroll
    for (int ofs = 1; ofs < 16; ofs <<= 1) {  // reduce within 16-lane head group
      ps += __shfl_xor(ps, ofs);
      pd += __shfl_xor(pd, ofs);
    }
    if ((lane & 15) == 0) { als[n * 4 + h] = ps; ald[n * 4 + h] = pd; }
  }
}

// ---------------- per-dst-node softmax aggregation ----------------
// one wave per node; lane l -> flat channels 4l..4l+3 (head l>>4).
// y fp32 [N,64]; saved (optional) fp32 [N,64]
__global__ __launch_bounds__(256) void agg_kernel(
    const unsigned short* __restrict__ xh,
    const float* __restrict__ als, const float* __restrict__ ald,
    const int* __restrict__ offsets, const int* __restrict__ csr_src,
    const void* __restrict__ bias, const int* __restrict__ flags,
    float* __restrict__ y, float* __restrict__ saved, int N) {
  int lane = threadIdx.x & 63;
  int wid = threadIdx.x >> 6;
  int n = blockIdx.x * 4 + wid;
  if (n >= N) return;
  int h = lane >> 4;
  float ad = ald[n * 4 + h];
  // implicit self loop (PyG add_self_loops)
  float e = als[n * 4 + h] + ad;
  e = (e > 0.f) ? e : NEG_SLOPE * e;
  e = fminf(fmaxf(e, -60.f), 60.f);          // safety clamp (no-op for sane data)
  float p = __expf(e);
  float dsum = p;
  ushort4 x4 = ((const ushort4*)xh)[(long long)n * 64 + lane];
  float a0 = p * bf2f(x4.x), a1 = p * bf2f(x4.y), a2 = p * bf2f(x4.z), a3 = p * bf2f(x4.w);
  int beg = offsets[n], end = offsets[n + 1];
  for (int j = beg; j < end; j++) {
    int s = csr_src[j];
    s = (s < 0 || s >= N) ? 0 : s;           // safety clamp
    float e2 = als[s * 4 + h] + ad;
    e2 = (e2 > 0.f) ? e2 : NEG_SLOPE * e2;
    e2 = fminf(fmaxf(e2, -60.f), 60.f);
    float p2 = __expf(e2);
    dsum += p2;
    ushort4 v = ((const ushort4*)xh)[(long long)s * 64 + lane];
    a0 += p2 * bf2f(v.x);
    a1 += p2 * bf2f(v.y);
    a2 += p2 * bf2f(v.z);
    a3 += p2 * bf2f(v.w);
  }
  float inv = 1.0f / fmaxf(dsum, 1e-30f);
  a0 *= inv; a1 *= inv; a2 *= inv; a3 *= inv;
  // mean over 4 heads: flat channel c lives in lanes {c>>2, +16h}
  a0 += __shfl_xor(a0, 16); a0 += __shfl_xor(a0, 32);
  a1 += __shfl_xor(a1, 16); a1 += __shfl_xor(a1, 32);
  a2 += __shfl_xor(a2, 16); a2 += __shfl_xor(a2, 32);
  a3 += __shfl_xor(a3, 16); a3 += __shfl_xor(a3, 32);
  if (lane < 16) {
    int f32 = flags[0];
    float4 o;
    o.x = 0.25f * a0 + loadF(bias, 4 * lane + 0, f32);
    o.y = 0.25f * a1 + loadF(bias, 4 * lane + 1, f32);
    o.z = 0.25f * a2 + loadF(bias, 4 * lane + 2, f32);
    o.w = 0.25f * a3 + loadF(bias, 4 * lane + 3, f32);
    ((float4*)(y + (size_t)n * 64))[lane] = o;
    if (saved) ((float4*)(saved + (size_t)n * 64))[lane] = o;  // fp32 output
  }
}

// ---------------- BN stats (per-channel sum / sumsq) ----------------
__global__ __launch_bounds__(256) void stats_kernel(const float* __restrict__ y,
                                                    float* __restrict__ gsum,
                                                    float* __restrict__ gsq, int N) {
  __shared__ float ls[256], lq[256];
  int t = threadIdx.x;
  int c = t & 63;
  int r0 = blockIdx.x * 4 + (t >> 6);
  float s = 0.f, q = 0.f;
  for (int r = r0; r < N; r += gridDim.x * 4) {
    float v = y[(size_t)r * 64 + c];
    s += v; q += v * v;
  }
  ls[t] = s; lq[t] = q;
  __syncthreads();
  if (t < 64) {
    s = ls[t] + ls[t + 64] + ls[t + 128] + ls[t + 192];
    q = lq[t] + lq[t + 64] + lq[t + 128] + lq[t + 192];
    atomicAdd(&gsum[c], s);
    atomicAdd(&gsq[c], q);
  }
}

// ---------------- BN apply + ReLU ----------------
// out_f (fp32, optional) and/or out_b (bf16, optional)
__global__ __launch_bounds__(256) void bn_kernel(
    const float* __restrict__ y, const float* __restrict__ gsum, const float* __restrict__ gsq,
    const void* __restrict__ gamma, const void* __restrict__ beta,
    const int* __restrict__ flags, float* __restrict__ out_f,
    unsigned short* __restrict__ out_b, int N) {
  int i = blockIdx.x * 256 + threadIdx.x;  // one float4 (4 channels) per thread
  if (i >= N * 16) return;
  int f32 = flags[0];
  int cg = i & 15;
  float4 v = ((const float4*)y)[i];
  float4 s = ((const float4*)gsum)[cg];
  float4 q = ((const float4*)gsq)[cg];
  float inv_n = 1.0f / (float)N;
  float vv[4] = {v.x, v.y, v.z, v.w};
  float ss[4] = {s.x, s.y, s.z, s.w};
  float qq[4] = {q.x, q.y, q.z, q.w};
  float o[4];
  #pragma unroll
  for (int k = 0; k < 4; k++) {
    float g = loadF(gamma, 4 * cg + k, f32);
    float b = loadF(beta, 4 * cg + k, f32);
    float mu = ss[k] * inv_n;
    float var = fmaxf(qq[k] * inv_n - mu * mu, 0.f);
    float r = g * (vv[k] - mu) * rsqrtf(var + BN_EPS) + b;
    o[k] = r > 0.f ? r : 0.f;
  }
  if (out_f) {
    float4 ov; ov.x = o[0]; ov.y = o[1]; ov.z = o[2]; ov.w = o[3];
    ((float4*)out_f)[i] = ov;
  }
  if (out_b) {
    ushort4 ov;
    ov.x = f2bf(o[0]); ov.y = f2bf(o[1]); ov.z = f2bf(o[2]); ov.w = f2bf(o[3]);
    ((ushort4*)out_b)[i] = ov;
  }
}

// ---------------- launch ----------------
extern "C" void kernel_launch(void* const* d_in, const int* in_sizes, int n_in,
                              void* d_out, int out_size, void* d_ws, size_t ws_size,
                              hipStream_t stream) {
  const void* x    = d_in[0];
  const void* ei   = d_in[1];
  // d_in[2] edge_weight: ignored (edge_dim=None in reference)
  const void* W0    = d_in[3];
  const void* asrc0 = d_in[4];
  const void* adst0 = d_in[5];
  const void* b0    = d_in[6];
  const void* g0    = d_in[7];
  const void* be0   = d_in[8];
  const void* W1    = d_in[9];
  const void* asrc1 = d_in[10];
  const void* adst1 = d_in[11];
  const void* b1    = d_in[12];
  const void* g1    = d_in[13];
  const void* be1   = d_in[14];

  int N = in_sizes[0] / 64;
  int E = in_sizes[1] / 2;
  int NB = (N + 255) / 256;  // scan blocks

  // workspace carve (256B aligned chunks)
  char* p = (char*)d_ws;
  auto alloc = [&](size_t bytes) -> char* {
    char* r = p;
    p += (bytes + 255) & ~(size_t)255;
    return r;
  };
  int* flags    = (int*)alloc(256);
  int* deg      = (int*)alloc((size_t)N * 4);
  int* cursor   = (int*)alloc((size_t)N * 4);
  int* offsets  = (int*)alloc((size_t)(N + 1) * 4);
  int* blocksum = (int*)alloc((size_t)NB * 4);
  int* blockbase= (int*)alloc((size_t)(NB + 1) * 4);
  int* csr_src  = (int*)alloc((size_t)E * 4);
  unsigned short* xh = (unsigned short*)alloc((size_t)N * 256 * 2);
  float* als    = (float*)alloc((size_t)N * 4 * 4);
  float* ald    = (float*)alloc((size_t)N * 4 * 4);
  float* y      = (float*)alloc((size_t)N * 64 * 4);
  unsigned short* x2 = (unsigned short*)alloc((size_t)N * 64 * 2);
  float* gsum0  = (float*)alloc(256);
  float* gsq0   = (float*)alloc(256);
  float* gsum1  = (float*)alloc(256);
  float* gsq1   = (float*)alloc(256);

  hipMemsetAsync(deg, 0, (size_t)N * 4, stream);
  hipMemsetAsync(cursor, 0, (size_t)N * 4, stream);
  hipMemsetAsync(gsum0, 0, 1024, stream);  // gsum0..gsq1 contiguous 4x256B

  detect_kernel<<<1, 256, 0, stream>>>((const unsigned short*)x, (const int*)ei, flags);

  // CSR build (shared by both layers) — hierarchical scan
  hist_kernel<<<(E + 255) / 256, 256, 0, stream>>>(ei, E, N, flags, deg);
  partial_kernel<<<NB, 256, 0, stream>>>(deg, blocksum, N);
  scan_base_kernel<<<1, 64, 0, stream>>>(blocksum, blockbase, NB);
  scan_final_kernel<<<NB, 256, 0, stream>>>(deg, blockbase, offsets, N);
  scatter_kernel<<<(E + 255) / 256, 256, 0, stream>>>(ei, E, N, flags, offsets, cursor, csr_src);

  float* out_x = (float*)d_out;                    // output 0: final (post BN+ReLU), fp32
  float* out_saved = out_x + (size_t)N * 64;       // output 1: layer-2 pre-BN, fp32

  // ---- layer 0 ----
  gemm_al_kernel<<<512, 256, 0, stream>>>(x, W0, asrc0, adst0, flags, 1, xh, als, ald, N);
  agg_kernel<<<(N + 3) / 4, 256, 0, stream>>>(xh, als, ald, offsets, csr_src, b0, flags, y,
                                              (float*)nullptr, N);
  stats_kernel<<<120, 256, 0, stream>>>(y, gsum0, gsq0, N);
  bn_kernel<<<(N * 16 + 255) / 256, 256, 0, stream>>>(y, gsum0, gsq0, g0, be0, flags,
                                                      (float*)nullptr, x2, N);

  // ---- layer 1 ----
  gemm_al_kernel<<<512, 256, 0, stream>>>(x2, W1, asrc1, adst1, flags, 0, xh, als, ald, N);
  agg_kernel<<<(N + 3) / 4, 256, 0, stream>>>(xh, als, ald, offsets, csr_src, b1, flags, y,
                                              out_saved, N);
  stats_kernel<<<120, 256, 0, stream>>>(y, gsum1, gsq1, N);
  bn_kernel<<<(N * 16 + 255) / 256, 256, 0, stream>>>(y, gsum1, gsq1, g1, be1, flags,
                                                      out_x, (unsigned short*)nullptr, N);
}

// Round 5
// 530.029 us; speedup vs baseline: 1.9021x; 1.2287x over previous
//
#include <hip/hip_runtime.h>
#include <stdint.h>

#define NEG_SLOPE 0.2f
#define BN_EPS 1e-5f

typedef __attribute__((ext_vector_type(8))) short bf16x8;
typedef __attribute__((ext_vector_type(4))) float f32x4;

// ---------------- bf16 helpers ----------------
__device__ __forceinline__ float bf2f(unsigned short u) {
  union { unsigned int i; float f; } v; v.i = ((unsigned int)u) << 16; return v.f;
}
__device__ __forceinline__ unsigned short f2bf(float f) {
  union { float f; unsigned int i; } v; v.f = f;
  unsigned int i = v.i;
  return (unsigned short)((i + 0x7fffu + ((i >> 16) & 1u)) >> 16);  // RNE
}
// flexible float load: f32 ? fp32 : bf16
__device__ __forceinline__ float loadF(const void* p, long long i, int f32) {
  return f32 ? ((const float*)p)[i] : bf2f(((const unsigned short*)p)[i]);
}
__device__ __forceinline__ int edge_at(const void* ei, long long idx, int is64) {
  return is64 ? (int)((const long long*)ei)[idx] : ((const int*)ei)[idx];
}

// ---------------- input dtype detection ----------------
// flags[0] = 1 if float inputs are fp32 (not bf16); flags[1] = 1 if edge_index is int64
__global__ void detect_kernel(const unsigned short* __restrict__ x,
                              const int* __restrict__ ei32,
                              int* __restrict__ flags) {
  __shared__ int wild, oddnz;
  if (threadIdx.x == 0) { wild = 0; oddnz = 0; }
  __syncthreads();
  int lw = 0, lo = 0;
  for (int i = threadIdx.x; i < 4096; i += 256) {
    unsigned short u = x[i];
    int ex = (u >> 7) & 0xFF;          // bf16 exponent field
    if (ex >= 0x86) lw++;              // |v| >= 128 or inf/nan: impossible for N(0,1) bf16
    if (ei32[2 * i + 1] != 0) lo++;    // int64 values < 2^31 -> high words all zero
  }
  if (lw) atomicAdd(&wild, lw);
  if (lo) atomicAdd(&oddnz, lo);
  __syncthreads();
  if (threadIdx.x == 0) { flags[0] = (wild > 64) ? 1 : 0; flags[1] = (oddnz == 0) ? 1 : 0; }
}

// ---------------- CSR build ----------------
__global__ __launch_bounds__(256) void hist_kernel(const void* __restrict__ ei, int E, int N,
                                                   const int* __restrict__ flags,
                                                   int* __restrict__ deg) {
  int e = blockIdx.x * 256 + threadIdx.x;
  if (e >= E) return;
  int is64 = flags[1];
  int d = edge_at(ei, (long long)E + e, is64);
  d = (d < 0 || d >= N) ? 0 : d;
  atomicAdd(&deg[d], 1);
}

// ---- hierarchical scan: 3 kernels ----
__global__ __launch_bounds__(256) void partial_kernel(const int* __restrict__ deg,
                                                      int* __restrict__ blocksum, int N) {
  int t = threadIdx.x;
  int idx = blockIdx.x * 256 + t;
  int v = (idx < N) ? deg[idx] : 0;
  #pragma unroll
  for (int o = 1; o < 64; o <<= 1) v += __shfl_xor(v, o);
  __shared__ int ws[4];
  if ((t & 63) == 0) ws[t >> 6] = v;
  __syncthreads();
  if (t == 0) blocksum[blockIdx.x] = ws[0] + ws[1] + ws[2] + ws[3];
}

__global__ void scan_base_kernel(const int* __restrict__ blocksum,
                                 int* __restrict__ blockbase, int B) {
  int lane = threadIdx.x;  // 64 threads
  int base = 0;
  if (lane == 0) blockbase[0] = 0;
  for (int start = 0; start < B; start += 64) {
    int idx = start + lane;
    int v = (idx < B) ? blocksum[idx] : 0;
    int sc = v;
    #pragma unroll
    for (int o = 1; o < 64; o <<= 1) {
      int u = __shfl_up(sc, o);
      if (lane >= o) sc += u;
    }
    if (idx < B) blockbase[idx + 1] = base + sc;
    base = __shfl(base + sc, 63);
  }
}

__global__ __launch_bounds__(256) void scan_final_kernel(const int* __restrict__ deg,
                                                         const int* __restrict__ blockbase,
                                                         int* __restrict__ offsets, int N) {
  int t = threadIdx.x;
  int lane = t & 63;
  int wid = t >> 6;
  int idx = blockIdx.x * 256 + t;
  int v = (idx < N) ? deg[idx] : 0;
  int sc = v;
  #pragma unroll
  for (int o = 1; o < 64; o <<= 1) {
    int u = __shfl_up(sc, o);
    if (lane >= o) sc += u;
  }
  __shared__ int ws[4];
  if (lane == 63) ws[wid] = sc;
  __syncthreads();
  int add = 0;
  #pragma unroll
  for (int w = 0; w < 4; w++) if (w < wid) add += ws[w];
  if (idx < N) offsets[idx + 1] = blockbase[blockIdx.x] + add + sc;
  if (idx == 0) offsets[0] = 0;
}

__global__ __launch_bounds__(256) void scatter_kernel(
    const void* __restrict__ ei, int E, int N, const int* __restrict__ flags,
    const int* __restrict__ offsets, int* __restrict__ cursor,
    int* __restrict__ csr_src) {
  int e = blockIdx.x * 256 + threadIdx.x;
  if (e >= E) return;
  int is64 = flags[1];
  int s = edge_at(ei, e, is64);
  int d = edge_at(ei, (long long)E + e, is64);
  s = (s < 0 || s >= N) ? 0 : s;
  d = (d < 0 || d >= N) ? 0 : d;
  int pos = offsets[d] + atomicAdd(&cursor[d], 1);
  csr_src[pos] = s;
}

// ---------------- MFMA: xh = x @ W  + attention logits ----------------
// x [N,64] (fp32 or bf16), W [64,256] -> xh bf16 [N,256], als/ald fp32 [N,4]
// Block: 256 thr = 4 waves; wave w computes rows m0 = blk*64 + w*16 .. +15, all 256 cols.
// A/B frag layout: [idx = lane&15][k = (lane>>4)*8 + j]; C/D: col=lane&15, row=(lane>>4)*4+reg.
__global__ __launch_bounds__(256, 2) void gemm_al_mfma(
    const void* __restrict__ x, const void* __restrict__ W,
    const void* __restrict__ a_src, const void* __restrict__ a_dst,
    const int* __restrict__ flags, int x_flex,
    unsigned short* __restrict__ xh, float* __restrict__ als, float* __restrict__ ald,
    int N) {
  __shared__ unsigned short WT[256 * 72];  // W^T bf16, row stride 72 (pad 8 -> 2-way banks, free)
  __shared__ float asd[512];               // a_src[256], a_dst[256] fp32
  int f32 = flags[0];
  int xf = x_flex ? f32 : 0;
  int t = threadIdx.x;
  // stage W^T (transpose): idx4 = k*64 + c4; read 4 consecutive cols, scatter to WT
  #pragma unroll
  for (int it = 0; it < 16; it++) {
    int idx4 = it * 256 + t;          // 4096 quads total
    int k = idx4 >> 6;
    int c = (idx4 & 63) * 4;
    unsigned short w0, w1, w2, w3;
    if (f32) {
      float4 w = ((const float4*)W)[idx4];
      w0 = f2bf(w.x); w1 = f2bf(w.y); w2 = f2bf(w.z); w3 = f2bf(w.w);
    } else {
      ushort4 w = ((const ushort4*)W)[idx4];
      w0 = w.x; w1 = w.y; w2 = w.z; w3 = w.w;
    }
    WT[(c + 0) * 72 + k] = w0;
    WT[(c + 1) * 72 + k] = w1;
    WT[(c + 2) * 72 + k] = w2;
    WT[(c + 3) * 72 + k] = w3;
  }
  if (t < 256) {
    asd[t] = loadF(a_src, t, f32);
    asd[256 + t] = loadF(a_dst, t, f32);
  }
  __syncthreads();

  int wave = t >> 6, lane = t & 63;
  int q = lane >> 4, r16 = lane & 15;
  int m0 = blockIdx.x * 64 + wave * 16;
  if (m0 >= N) return;
  int row = m0 + r16;
  int rowc = row < N ? row : N - 1;

  // A fragments: k-chunk 0 (k=q*8..q*8+7) and chunk 1 (+32)
  bf16x8 a0, a1;
  if (xf) {
    const float* xp = (const float*)x + (size_t)rowc * 64 + q * 8;
    float4 v0 = ((const float4*)xp)[0];
    float4 v1 = ((const float4*)xp)[1];
    float4 v2 = ((const float4*)(xp + 32))[0];
    float4 v3 = ((const float4*)(xp + 32))[1];
    a0[0] = (short)f2bf(v0.x); a0[1] = (short)f2bf(v0.y); a0[2] = (short)f2bf(v0.z); a0[3] = (short)f2bf(v0.w);
    a0[4] = (short)f2bf(v1.x); a0[5] = (short)f2bf(v1.y); a0[6] = (short)f2bf(v1.z); a0[7] = (short)f2bf(v1.w);
    a1[0] = (short)f2bf(v2.x); a1[1] = (short)f2bf(v2.y); a1[2] = (short)f2bf(v2.z); a1[3] = (short)f2bf(v2.w);
    a1[4] = (short)f2bf(v3.x); a1[5] = (short)f2bf(v3.y); a1[6] = (short)f2bf(v3.z); a1[7] = (short)f2bf(v3.w);
  } else {
    const unsigned short* xp = (const unsigned short*)x + (size_t)rowc * 64 + q * 8;
    a0 = *(const bf16x8*)xp;
    a1 = *(const bf16x8*)(xp + 32);
  }

  f32x4 acc[16];
  #pragma unroll
  for (int tt = 0; tt < 16; tt++) acc[tt] = (f32x4){0.f, 0.f, 0.f, 0.f};
  #pragma unroll
  for (int tt = 0; tt < 16; tt++) {
    int c = tt * 16 + r16;
    bf16x8 b0 = *(const bf16x8*)&WT[c * 72 + q * 8];
    bf16x8 b1 = *(const bf16x8*)&WT[c * 72 + 32 + q * 8];
    acc[tt] = __builtin_amdgcn_mfma_f32_16x16x32_bf16(a0, b0, acc[tt], 0, 0, 0);
    acc[tt] = __builtin_amdgcn_mfma_f32_16x16x32_bf16(a1, b1, acc[tt], 0, 0, 0);
  }

  // epilogue: store xh bf16 + per-head logit partials
  float ps[4][4], pd[4][4];  // [reg/row][head]
  #pragma unroll
  for (int rr = 0; rr < 4; rr++)
    #pragma unroll
    for (int h = 0; h < 4; h++) { ps[rr][h] = 0.f; pd[rr][h] = 0.f; }
  #pragma unroll
  for (int tt = 0; tt < 16; tt++) {
    int c = tt * 16 + r16;
    int h = tt >> 2;               // all 16 cols of tile tt belong to head tt>>2
    float av = asd[c], dv = asd[256 + c];
    #pragma unroll
    for (int rr = 0; rr < 4; rr++) {
      float v = acc[tt][rr];
      ps[rr][h] += v * av;
      pd[rr][h] += v * dv;
      int orow = m0 + q * 4 + rr;
      if (orow < N) xh[(size_t)orow * 256 + c] = f2bf(v);
    }
  }
  // butterfly-reduce over the 16 lanes of each quad group
  #pragma unroll
  for (int rr = 0; rr < 4; rr++)
    #pragma unroll
    for (int h = 0; h < 4; h++) {
      #pragma unroll
      for (int o = 1; o < 16; o <<= 1) {
        ps[rr][h] += __shfl_xor(ps[rr][h], o);
        pd[rr][h] += __shfl_xor(pd[rr][h], o);
      }
    }
  int obase = m0 + q * 4;
  if (r16 < 4) {
    #pragma unroll
    for (int rr = 0; rr < 4; rr++)
      if (obase + rr < N) als[(obase + rr) * 4 + r16] = ps[rr][r16];
  } else if (r16 < 8) {
    int h = r16 - 4;
    #pragma unroll
    for (int rr = 0; rr < 4; rr++)
      if (obase + rr < N) ald[(obase + rr) * 4 + h] = pd[rr][h];
  }
}

// ---------------- per-dst-node softmax aggregation ----------------
__global__ __launch_bounds__(256) void agg_kernel(
    const unsigned short* __restrict__ xh,
    const float* __restrict__ als, const float* __restrict__ ald,
    const int* __restrict__ offsets, const int* __restrict__ csr_src,
    const void* __restrict__ bias, const int* __restrict__ flags,
    float* __restrict__ y, float* __restrict__ saved, int N) {
  int lane = threadIdx.x & 63;
  int wid = threadIdx.x >> 6;
  int n = blockIdx.x * 4 + wid;
  if (n >= N) return;
  int h = lane >> 4;
  float ad = ald[n * 4 + h];
  float e = als[n * 4 + h] + ad;  // implicit self loop
  e = (e > 0.f) ? e : NEG_SLOPE * e;
  e = fminf(fmaxf(e, -60.f), 60.f);
  float p = __expf(e);
  float dsum = p;
  ushort4 x4 = ((const ushort4*)xh)[(long long)n * 64 + lane];
  float a0 = p * bf2f(x4.x), a1 = p * bf2f(x4.y), a2 = p * bf2f(x4.z), a3 = p * bf2f(x4.w);
  int beg = offsets[n], end = offsets[n + 1];
  for (int j = beg; j < end; j++) {
    int s = csr_src[j];
    s = (s < 0 || s >= N) ? 0 : s;
    float e2 = als[s * 4 + h] + ad;
    e2 = (e2 > 0.f) ? e2 : NEG_SLOPE * e2;
    e2 = fminf(fmaxf(e2, -60.f), 60.f);
    float p2 = __expf(e2);
    dsum += p2;
    ushort4 v = ((const ushort4*)xh)[(long long)s * 64 + lane];
    a0 += p2 * bf2f(v.x);
    a1 += p2 * bf2f(v.y);
    a2 += p2 * bf2f(v.z);
    a3 += p2 * bf2f(v.w);
  }
  float inv = 1.0f / fmaxf(dsum, 1e-30f);
  a0 *= inv; a1 *= inv; a2 *= inv; a3 *= inv;
  a0 += __shfl_xor(a0, 16); a0 += __shfl_xor(a0, 32);
  a1 += __shfl_xor(a1, 16); a1 += __shfl_xor(a1, 32);
  a2 += __shfl_xor(a2, 16); a2 += __shfl_xor(a2, 32);
  a3 += __shfl_xor(a3, 16); a3 += __shfl_xor(a3, 32);
  if (lane < 16) {
    int f32 = flags[0];
    float4 o;
    o.x = 0.25f * a0 + loadF(bias, 4 * lane + 0, f32);
    o.y = 0.25f * a1 + loadF(bias, 4 * lane + 1, f32);
    o.z = 0.25f * a2 + loadF(bias, 4 * lane + 2, f32);
    o.w = 0.25f * a3 + loadF(bias, 4 * lane + 3, f32);
    ((float4*)(y + (size_t)n * 64))[lane] = o;
    if (saved) ((float4*)(saved + (size_t)n * 64))[lane] = o;
  }
}

// ---------------- BN stats (per-channel sum / sumsq) ----------------
__global__ __launch_bounds__(256) void stats_kernel(const float* __restrict__ y,
                                                    float* __restrict__ gsum,
                                                    float* __restrict__ gsq, int N) {
  __shared__ float ls[256], lq[256];
  int t = threadIdx.x;
  int c = t & 63;
  int r0 = blockIdx.x * 4 + (t >> 6);
  float s = 0.f, q = 0.f;
  for (int r = r0; r < N; r += gridDim.x * 4) {
    float v = y[(size_t)r * 64 + c];
    s += v; q += v * v;
  }
  ls[t] = s; lq[t] = q;
  __syncthreads();
  if (t < 64) {
    s = ls[t] + ls[t + 64] + ls[t + 128] + ls[t + 192];
    q = lq[t] + lq[t + 64] + lq[t + 128] + lq[t + 192];
    atomicAdd(&gsum[c], s);
    atomicAdd(&gsq[c], q);
  }
}

// ---------------- BN apply + ReLU ----------------
__global__ __launch_bounds__(256) void bn_kernel(
    const float* __restrict__ y, const float* __restrict__ gsum, const float* __restrict__ gsq,
    const void* __restrict__ gamma, const void* __restrict__ beta,
    const int* __restrict__ flags, float* __restrict__ out_f,
    unsigned short* __restrict__ out_b, int N) {
  int i = blockIdx.x * 256 + threadIdx.x;  // one float4 (4 channels) per thread
  if (i >= N * 16) return;
  int f32 = flags[0];
  int cg = i & 15;
  float4 v = ((const float4*)y)[i];
  float4 s = ((const float4*)gsum)[cg];
  float4 q = ((const float4*)gsq)[cg];
  float inv_n = 1.0f / (float)N;
  float vv[4] = {v.x, v.y, v.z, v.w};
  float ss[4] = {s.x, s.y, s.z, s.w};
  float qq[4] = {q.x, q.y, q.z, q.w};
  float o[4];
  #pragma unroll
  for (int k = 0; k < 4; k++) {
    float g = loadF(gamma, 4 * cg + k, f32);
    float b = loadF(beta, 4 * cg + k, f32);
    float mu = ss[k] * inv_n;
    float var = fmaxf(qq[k] * inv_n - mu * mu, 0.f);
    float r = g * (vv[k] - mu) * rsqrtf(var + BN_EPS) + b;
    o[k] = r > 0.f ? r : 0.f;
  }
  if (out_f) {
    float4 ov; ov.x = o[0]; ov.y = o[1]; ov.z = o[2]; ov.w = o[3];
    ((float4*)out_f)[i] = ov;
  }
  if (out_b) {
    ushort4 ov;
    ov.x = f2bf(o[0]); ov.y = f2bf(o[1]); ov.z = f2bf(o[2]); ov.w = f2bf(o[3]);
    ((ushort4*)out_b)[i] = ov;
  }
}

// ---------------- launch ----------------
extern "C" void kernel_launch(void* const* d_in, const int* in_sizes, int n_in,
                              void* d_out, int out_size, void* d_ws, size_t ws_size,
                              hipStream_t stream) {
  const void* x    = d_in[0];
  const void* ei   = d_in[1];
  // d_in[2] edge_weight: ignored (edge_dim=None in reference)
  const void* W0    = d_in[3];
  const void* asrc0 = d_in[4];
  const void* adst0 = d_in[5];
  const void* b0    = d_in[6];
  const void* g0    = d_in[7];
  const void* be0   = d_in[8];
  const void* W1    = d_in[9];
  const void* asrc1 = d_in[10];
  const void* adst1 = d_in[11];
  const void* b1    = d_in[12];
  const void* g1    = d_in[13];
  const void* be1   = d_in[14];

  int N = in_sizes[0] / 64;
  int E = in_sizes[1] / 2;
  int NB = (N + 255) / 256;   // scan blocks
  int NG = (N + 63) / 64;     // gemm blocks (64 rows each)

  // workspace carve (256B aligned chunks)
  char* p = (char*)d_ws;
  auto alloc = [&](size_t bytes) -> char* {
    char* r = p;
    p += (bytes + 255) & ~(size_t)255;
    return r;
  };
  int* flags    = (int*)alloc(256);
  int* deg      = (int*)alloc((size_t)N * 4);
  int* cursor   = (int*)alloc((size_t)N * 4);
  int* offsets  = (int*)alloc((size_t)(N + 1) * 4);
  int* blocksum = (int*)alloc((size_t)NB * 4);
  int* blockbase= (int*)alloc((size_t)(NB + 1) * 4);
  int* csr_src  = (int*)alloc((size_t)E * 4);
  unsigned short* xh = (unsigned short*)alloc((size_t)N * 256 * 2);
  float* als    = (float*)alloc((size_t)N * 4 * 4);
  float* ald    = (float*)alloc((size_t)N * 4 * 4);
  float* y      = (float*)alloc((size_t)N * 64 * 4);
  unsigned short* x2 = (unsigned short*)alloc((size_t)N * 64 * 2);
  float* gsum0  = (float*)alloc(256);
  float* gsq0   = (float*)alloc(256);
  float* gsum1  = (float*)alloc(256);
  float* gsq1   = (float*)alloc(256);

  hipMemsetAsync(deg, 0, (size_t)N * 4, stream);
  hipMemsetAsync(cursor, 0, (size_t)N * 4, stream);
  hipMemsetAsync(gsum0, 0, 1024, stream);  // gsum0..gsq1 contiguous 4x256B

  detect_kernel<<<1, 256, 0, stream>>>((const unsigned short*)x, (const int*)ei, flags);

  // CSR build (shared by both layers) — hierarchical scan
  hist_kernel<<<(E + 255) / 256, 256, 0, stream>>>(ei, E, N, flags, deg);
  partial_kernel<<<NB, 256, 0, stream>>>(deg, blocksum, N);
  scan_base_kernel<<<1, 64, 0, stream>>>(blocksum, blockbase, NB);
  scan_final_kernel<<<NB, 256, 0, stream>>>(deg, blockbase, offsets, N);
  scatter_kernel<<<(E + 255) / 256, 256, 0, stream>>>(ei, E, N, flags, offsets, cursor, csr_src);

  float* out_x = (float*)d_out;                    // output 0: final (post BN+ReLU), fp32
  float* out_saved = out_x + (size_t)N * 64;       // output 1: layer-2 pre-BN, fp32

  // ---- layer 0 ----
  gemm_al_mfma<<<NG, 256, 0, stream>>>(x, W0, asrc0, adst0, flags, 1, xh, als, ald, N);
  agg_kernel<<<(N + 3) / 4, 256, 0, stream>>>(xh, als, ald, offsets, csr_src, b0, flags, y,
                                              (float*)nullptr, N);
  stats_kernel<<<250, 256, 0, stream>>>(y, gsum0, gsq0, N);
  bn_kernel<<<(N * 16 + 255) / 256, 256, 0, stream>>>(y, gsum0, gsq0, g0, be0, flags,
                                                      (float*)nullptr, x2, N);

  // ---- layer 1 ----
  gemm_al_mfma<<<NG, 256, 0, stream>>>(x2, W1, asrc1, adst1, flags, 0, xh, als, ald, N);
  agg_kernel<<<(N + 3) / 4, 256, 0, stream>>>(xh, als, ald, offsets, csr_src, b1, flags, y,
                                              out_saved, N);
  stats_kernel<<<250, 256, 0, stream>>>(y, gsum1, gsq1, N);
  bn_kernel<<<(N * 16 + 255) / 256, 256, 0, stream>>>(y, gsum1, gsq1, g1, be1, flags,
                                                      out_x, (unsigned short*)nullptr, N);
}

// Round 6
// 464.938 us; speedup vs baseline: 2.1684x; 1.1400x over previous
//
#include <hip/hip_runtime.h>
#include <stdint.h>

#define NEG_SLOPE 0.2f
#define BN_EPS 1e-5f

typedef __attribute__((ext_vector_type(8))) short bf16x8;
typedef __attribute__((ext_vector_type(4))) float f32x4;

// ---------------- bf16 helpers ----------------
__device__ __forceinline__ float bf2f(unsigned short u) {
  union { unsigned int i; float f; } v; v.i = ((unsigned int)u) << 16; return v.f;
}
__device__ __forceinline__ float asf(unsigned int u) {
  union { unsigned int i; float f; } v; v.i = u; return v.f;
}
__device__ __forceinline__ unsigned short f2bf(float f) {
  union { float f; unsigned int i; } v; v.f = f;
  unsigned int i = v.i;
  return (unsigned short)((i + 0x7fffu + ((i >> 16) & 1u)) >> 16);  // RNE
}
__device__ __forceinline__ float loadF(const void* p, long long i, int f32) {
  return f32 ? ((const float*)p)[i] : bf2f(((const unsigned short*)p)[i]);
}
__device__ __forceinline__ int edge_at(const void* ei, long long idx, int is64) {
  return is64 ? (int)((const long long*)ei)[idx] : ((const int*)ei)[idx];
}

// ---------------- input dtype detection ----------------
__global__ void detect_kernel(const unsigned short* __restrict__ x,
                              const int* __restrict__ ei32,
                              int* __restrict__ flags) {
  __shared__ int wild, oddnz;
  if (threadIdx.x == 0) { wild = 0; oddnz = 0; }
  __syncthreads();
  int lw = 0, lo = 0;
  for (int i = threadIdx.x; i < 4096; i += 256) {
    unsigned short u = x[i];
    int ex = (u >> 7) & 0xFF;
    if (ex >= 0x86) lw++;
    if (ei32[2 * i + 1] != 0) lo++;
  }
  if (lw) atomicAdd(&wild, lw);
  if (lo) atomicAdd(&oddnz, lo);
  __syncthreads();
  if (threadIdx.x == 0) { flags[0] = (wild > 64) ? 1 : 0; flags[1] = (oddnz == 0) ? 1 : 0; }
}

// ---------------- W preprocessing (one launch, 2 blocks = 2 layers) ----------------
// WTx layout [272 rows][64 k] bf16: rows 0..255 = W^T (row c = W[:,c]);
// rows 256..259 = Ws[h][k] = sum_c W[k][h*64+c]*a_src[h*64+c]; 260..263 = Wd; 264..271 = 0.
__global__ __launch_bounds__(256) void wtrans_kernel(
    const void* __restrict__ W0, const void* __restrict__ as0, const void* __restrict__ ad0,
    const void* __restrict__ W1, const void* __restrict__ as1, const void* __restrict__ ad1,
    const int* __restrict__ flags, int layer1_bf16,
    unsigned short* __restrict__ WTx0, unsigned short* __restrict__ WTx1) {
  const void* W = blockIdx.x ? W1 : W0;
  const void* asrc = blockIdx.x ? as1 : as0;
  const void* adst = blockIdx.x ? ad1 : ad0;
  unsigned short* WTx = blockIdx.x ? WTx1 : WTx0;
  int f32 = flags[0];
  __shared__ unsigned short Wl[64 * 258];  // W[k][c] bf16, pad 2
  int t = threadIdx.x;
  for (int i = t; i < 64 * 256; i += 256) {
    int k = i >> 8, c = i & 255;
    Wl[k * 258 + c] = f32 ? f2bf(((const float*)W)[i]) : ((const unsigned short*)W)[i];
  }
  __syncthreads();
  // transpose: thread t = col c, write WTx[c][0..63]
  {
    int c = t;
    #pragma unroll
    for (int k8 = 0; k8 < 64; k8 += 8) {
      unsigned int p0 = (unsigned int)Wl[(k8 + 0) * 258 + c] | ((unsigned int)Wl[(k8 + 1) * 258 + c] << 16);
      unsigned int p1 = (unsigned int)Wl[(k8 + 2) * 258 + c] | ((unsigned int)Wl[(k8 + 3) * 258 + c] << 16);
      unsigned int p2 = (unsigned int)Wl[(k8 + 4) * 258 + c] | ((unsigned int)Wl[(k8 + 5) * 258 + c] << 16);
      unsigned int p3 = (unsigned int)Wl[(k8 + 6) * 258 + c] | ((unsigned int)Wl[(k8 + 7) * 258 + c] << 16);
      uint4 pk; pk.x = p0; pk.y = p1; pk.z = p2; pk.w = p3;
      *(uint4*)&WTx[c * 64 + k8] = pk;
    }
  }
  // Ws / Wd rows (8 rows x 64 k), 2 per thread
  for (int idx = t; idx < 512; idx += 256) {
    int r = idx >> 6;          // 0..7
    int k = idx & 63;
    int h = r & 3;
    const void* av = (r >> 2) ? adst : asrc;
    float acc = 0.f;
    #pragma unroll 8
    for (int c = 0; c < 64; c++)
      acc += bf2f(Wl[k * 258 + h * 64 + c]) * loadF(av, h * 64 + c, f32);
    WTx[(256 + r) * 64 + k] = f2bf(acc);
  }
  // zero pad rows 264..271
  for (int idx = t; idx < 512; idx += 256) WTx[264 * 64 + idx] = 0;
}

// ---------------- CSR build ----------------
__global__ __launch_bounds__(256) void hist_kernel(const void* __restrict__ ei, int E, int N,
                                                   const int* __restrict__ flags,
                                                   int* __restrict__ deg) {
  int e = blockIdx.x * 256 + threadIdx.x;
  if (e >= E) return;
  int is64 = flags[1];
  int d = edge_at(ei, (long long)E + e, is64);
  d = (d < 0 || d >= N) ? 0 : d;
  atomicAdd(&deg[d], 1);
}

__global__ __launch_bounds__(256) void partial_kernel(const int* __restrict__ deg,
                                                      int* __restrict__ blocksum, int N) {
  int t = threadIdx.x;
  int idx = blockIdx.x * 256 + t;
  int v = (idx < N) ? deg[idx] : 0;
  #pragma unroll
  for (int o = 1; o < 64; o <<= 1) v += __shfl_xor(v, o);
  __shared__ int ws[4];
  if ((t & 63) == 0) ws[t >> 6] = v;
  __syncthreads();
  if (t == 0) blocksum[blockIdx.x] = ws[0] + ws[1] + ws[2] + ws[3];
}

__global__ void scan_base_kernel(const int* __restrict__ blocksum,
                                 int* __restrict__ blockbase, int B) {
  int lane = threadIdx.x;
  int base = 0;
  if (lane == 0) blockbase[0] = 0;
  for (int start = 0; start < B; start += 64) {
    int idx = start + lane;
    int v = (idx < B) ? blocksum[idx] : 0;
    int sc = v;
    #pragma unroll
    for (int o = 1; o < 64; o <<= 1) {
      int u = __shfl_up(sc, o);
      if (lane >= o) sc += u;
    }
    if (idx < B) blockbase[idx + 1] = base + sc;
    base = __shfl(base + sc, 63);
  }
}

__global__ __launch_bounds__(256) void scan_final_kernel(const int* __restrict__ deg,
                                                         const int* __restrict__ blockbase,
                                                         int* __restrict__ offsets, int N) {
  int t = threadIdx.x;
  int lane = t & 63;
  int wid = t >> 6;
  int idx = blockIdx.x * 256 + t;
  int v = (idx < N) ? deg[idx] : 0;
  int sc = v;
  #pragma unroll
  for (int o = 1; o < 64; o <<= 1) {
    int u = __shfl_up(sc, o);
    if (lane >= o) sc += u;
  }
  __shared__ int ws[4];
  if (lane == 63) ws[wid] = sc;
  __syncthreads();
  int add = 0;
  #pragma unroll
  for (int w = 0; w < 4; w++) if (w < wid) add += ws[w];
  if (idx < N) offsets[idx + 1] = blockbase[blockIdx.x] + add + sc;
  if (idx == 0) offsets[0] = 0;
}

__global__ __launch_bounds__(256) void scatter_kernel(
    const void* __restrict__ ei, int E, int N, const int* __restrict__ flags,
    const int* __restrict__ offsets, int* __restrict__ cursor,
    int* __restrict__ csr_src) {
  int e = blockIdx.x * 256 + threadIdx.x;
  if (e >= E) return;
  int is64 = flags[1];
  int s = edge_at(ei, e, is64);
  int d = edge_at(ei, (long long)E + e, is64);
  s = (s < 0 || s >= N) ? 0 : s;
  d = (d < 0 || d >= N) ? 0 : d;
  int pos = offsets[d] + atomicAdd(&cursor[d], 1);
  csr_src[pos] = s;
}

// ---------------- MFMA GEMM: xh = x @ W (bf16 out) + als/ald via extra tile ----------------
// 4 waves/block; wave w owns rows m0 = blk*64 + w*16 .. +15. 17 tiles: 0..15 = xh cols,
// tile 16 = [als heads 0..3 | ald heads 0..3 | zero pad] from WTx rows 256..271.
// A/B frag: [idx=lane&15][k=(lane>>4)*8+j]; C/D: col=lane&15, row=(lane>>4)*4+reg. (HW-verified r4)
__global__ __launch_bounds__(256, 2) void gemm_mfma(
    const void* __restrict__ x, const unsigned short* __restrict__ WTx,
    const int* __restrict__ flags, int x_flex,
    unsigned short* __restrict__ xh, float* __restrict__ als, float* __restrict__ ald,
    int N) {
  __shared__ unsigned short RP[4][16 * 264];  // per-wave repack tile [16 rows][264]
  int f32 = flags[0];
  int xf = x_flex ? f32 : 0;
  int t = threadIdx.x;
  int wave = t >> 6, lane = t & 63;
  int q = lane >> 4, r16 = lane & 15;
  int m0 = blockIdx.x * 64 + wave * 16;
  if (m0 >= N) return;
  int row = m0 + r16;
  int rowc = row < N ? row : N - 1;

  // A fragments (k chunks 0 and 1)
  bf16x8 a0, a1;
  if (xf) {
    const float* xp = (const float*)x + (size_t)rowc * 64 + q * 8;
    float4 v0 = ((const float4*)xp)[0];
    float4 v1 = ((const float4*)xp)[1];
    float4 v2 = ((const float4*)(xp + 32))[0];
    float4 v3 = ((const float4*)(xp + 32))[1];
    a0[0] = (short)f2bf(v0.x); a0[1] = (short)f2bf(v0.y); a0[2] = (short)f2bf(v0.z); a0[3] = (short)f2bf(v0.w);
    a0[4] = (short)f2bf(v1.x); a0[5] = (short)f2bf(v1.y); a0[6] = (short)f2bf(v1.z); a0[7] = (short)f2bf(v1.w);
    a1[0] = (short)f2bf(v2.x); a1[1] = (short)f2bf(v2.y); a1[2] = (short)f2bf(v2.z); a1[3] = (short)f2bf(v2.w);
    a1[4] = (short)f2bf(v3.x); a1[5] = (short)f2bf(v3.y); a1[6] = (short)f2bf(v3.z); a1[7] = (short)f2bf(v3.w);
  } else {
    const unsigned short* xp = (const unsigned short*)x + (size_t)rowc * 64 + q * 8;
    a0 = *(const bf16x8*)xp;
    a1 = *(const bf16x8*)(xp + 32);
  }

  f32x4 acc[17];
  #pragma unroll
  for (int tt = 0; tt < 17; tt++) acc[tt] = (f32x4){0.f, 0.f, 0.f, 0.f};
  #pragma unroll
  for (int tt = 0; tt < 17; tt++) {
    int c = tt * 16 + r16;
    bf16x8 b0 = *(const bf16x8*)(WTx + c * 64 + q * 8);
    bf16x8 b1 = *(const bf16x8*)(WTx + c * 64 + 32 + q * 8);
    acc[tt] = __builtin_amdgcn_mfma_f32_16x16x32_bf16(a0, b0, acc[tt], 0, 0, 0);
    acc[tt] = __builtin_amdgcn_mfma_f32_16x16x32_bf16(a1, b1, acc[tt], 0, 0, 0);
  }

  // ---- epilogue 1: als/ald from tile 16 (col r16: 0..3 = als head, 4..7 = ald head) ----
  {
    int obase = m0 + q * 4;
    #pragma unroll
    for (int rr = 0; rr < 4; rr++) {
      int orow = obase + rr;
      if (orow < N) {
        if (r16 < 4) als[orow * 4 + r16] = acc[16][rr];
        else if (r16 < 8) ald[orow * 4 + (r16 - 4)] = acc[16][rr];
      }
    }
  }
  // ---- epilogue 2: repack tiles 0..15 to row-major LDS, then coalesced 16B stores ----
  unsigned short* rp = RP[wave];
  #pragma unroll
  for (int tt = 0; tt < 16; tt++) {
    #pragma unroll
    for (int rr = 0; rr < 4; rr++)
      rp[(q * 4 + rr) * 264 + tt * 16 + r16] = f2bf(acc[tt][rr]);
  }
  // wave-internal LDS visibility only (compiler inserts lgkmcnt wait)
  #pragma unroll
  for (int i = 0; i < 8; i++) {
    int g = i * 64 + lane;          // flat uint4 group
    int r = g >> 5;                 // row 0..15
    int grp = g & 31;               // 8-ushort group in row
    uint4 v = *(const uint4*)&rp[r * 264 + grp * 8];
    int orow = m0 + r;
    if (orow < N) ((uint4*)xh)[(size_t)orow * 32 + grp] = v;
  }
}

// ---------------- per-dst-node softmax aggregation ----------------
// one wave per node; lane l -> channels 4l..4l+3 (head l>>4). 2-edge unrolled.
__global__ __launch_bounds__(256) void agg_kernel(
    const unsigned short* __restrict__ xh,
    const float* __restrict__ als, const float* __restrict__ ald,
    const int* __restrict__ offsets, const int* __restrict__ csr_src,
    const void* __restrict__ bias, const int* __restrict__ flags,
    float* __restrict__ y, float* __restrict__ saved, int N) {
  int lane = threadIdx.x & 63;
  int wid = threadIdx.x >> 6;
  int n = blockIdx.x * 4 + wid;
  if (n >= N) return;
  int h = lane >> 4;
  const uint2* xv = (const uint2*)xh;
  float ad = ald[n * 4 + h];
  float e = als[n * 4 + h] + ad;  // implicit self loop
  e = (e > 0.f) ? e : NEG_SLOPE * e;
  float p = __expf(e);
  float dsum = p;
  uint2 xs = xv[(size_t)n * 64 + lane];
  float a0 = p * asf(xs.x << 16), a1 = p * asf(xs.x & 0xffff0000u);
  float a2 = p * asf(xs.y << 16), a3 = p * asf(xs.y & 0xffff0000u);
  int beg = offsets[n], end = offsets[n + 1];
  int j = beg;
  for (; j + 2 <= end; j += 2) {
    int s0 = csr_src[j];
    int s1 = csr_src[j + 1];
    uint2 v0 = xv[(size_t)s0 * 64 + lane];
    uint2 v1 = xv[(size_t)s1 * 64 + lane];
    float e0 = als[s0 * 4 + h] + ad;
    float e1 = als[s1 * 4 + h] + ad;
    e0 = (e0 > 0.f) ? e0 : NEG_SLOPE * e0;
    e1 = (e1 > 0.f) ? e1 : NEG_SLOPE * e1;
    float p0 = __expf(e0);
    float p1 = __expf(e1);
    dsum += p0 + p1;
    a0 += p0 * asf(v0.x << 16) + p1 * asf(v1.x << 16);
    a1 += p0 * asf(v0.x & 0xffff0000u) + p1 * asf(v1.x & 0xffff0000u);
    a2 += p0 * asf(v0.y << 16) + p1 * asf(v1.y << 16);
    a3 += p0 * asf(v0.y & 0xffff0000u) + p1 * asf(v1.y & 0xffff0000u);
  }
  if (j < end) {
    int s0 = csr_src[j];
    uint2 v0 = xv[(size_t)s0 * 64 + lane];
    float e0 = als[s0 * 4 + h] + ad;
    e0 = (e0 > 0.f) ? e0 : NEG_SLOPE * e0;
    float p0 = __expf(e0);
    dsum += p0;
    a0 += p0 * asf(v0.x << 16);
    a1 += p0 * asf(v0.x & 0xffff0000u);
    a2 += p0 * asf(v0.y << 16);
    a3 += p0 * asf(v0.y & 0xffff0000u);
  }
  float inv = 1.0f / dsum;
  a0 *= inv; a1 *= inv; a2 *= inv; a3 *= inv;
  // mean over 4 heads
  a0 += __shfl_xor(a0, 16); a0 += __shfl_xor(a0, 32);
  a1 += __shfl_xor(a1, 16); a1 += __shfl_xor(a1, 32);
  a2 += __shfl_xor(a2, 16); a2 += __shfl_xor(a2, 32);
  a3 += __shfl_xor(a3, 16); a3 += __shfl_xor(a3, 32);
  if (lane < 16) {
    int f32 = flags[0];
    float4 o;
    o.x = 0.25f * a0 + loadF(bias, 4 * lane + 0, f32);
    o.y = 0.25f * a1 + loadF(bias, 4 * lane + 1, f32);
    o.z = 0.25f * a2 + loadF(bias, 4 * lane + 2, f32);
    o.w = 0.25f * a3 + loadF(bias, 4 * lane + 3, f32);
    ((float4*)(y + (size_t)n * 64))[lane] = o;
    if (saved) ((float4*)(saved + (size_t)n * 64))[lane] = o;
  }
}

// ---------------- BN stats ----------------
__global__ __launch_bounds__(256) void stats_kernel(const float* __restrict__ y,
                                                    float* __restrict__ gsum,
                                                    float* __restrict__ gsq, int N) {
  __shared__ float ls[256], lq[256];
  int t = threadIdx.x;
  int c = t & 63;
  int r0 = blockIdx.x * 4 + (t >> 6);
  float s = 0.f, q = 0.f;
  for (int r = r0; r < N; r += gridDim.x * 4) {
    float v = y[(size_t)r * 64 + c];
    s += v; q += v * v;
  }
  ls[t] = s; lq[t] = q;
  __syncthreads();
  if (t < 64) {
    s = ls[t] + ls[t + 64] + ls[t + 128] + ls[t + 192];
    q = lq[t] + lq[t + 64] + lq[t + 128] + lq[t + 192];
    atomicAdd(&gsum[c], s);
    atomicAdd(&gsq[c], q);
  }
}

// ---------------- BN apply + ReLU ----------------
__global__ __launch_bounds__(256) void bn_kernel(
    const float* __restrict__ y, const float* __restrict__ gsum, const float* __restrict__ gsq,
    const void* __restrict__ gamma, const void* __restrict__ beta,
    const int* __restrict__ flags, float* __restrict__ out_f,
    unsigned short* __restrict__ out_b, int N) {
  int i = blockIdx.x * 256 + threadIdx.x;
  if (i >= N * 16) return;
  int f32 = flags[0];
  int cg = i & 15;
  float4 v = ((const float4*)y)[i];
  float4 s = ((const float4*)gsum)[cg];
  float4 q = ((const float4*)gsq)[cg];
  float inv_n = 1.0f / (float)N;
  float vv[4] = {v.x, v.y, v.z, v.w};
  float ss[4] = {s.x, s.y, s.z, s.w};
  float qq[4] = {q.x, q.y, q.z, q.w};
  float o[4];
  #pragma unroll
  for (int k = 0; k < 4; k++) {
    float g = loadF(gamma, 4 * cg + k, f32);
    float b = loadF(beta, 4 * cg + k, f32);
    float mu = ss[k] * inv_n;
    float var = fmaxf(qq[k] * inv_n - mu * mu, 0.f);
    float r = g * (vv[k] - mu) * rsqrtf(var + BN_EPS) + b;
    o[k] = r > 0.f ? r : 0.f;
  }
  if (out_f) {
    float4 ov; ov.x = o[0]; ov.y = o[1]; ov.z = o[2]; ov.w = o[3];
    ((float4*)out_f)[i] = ov;
  }
  if (out_b) {
    ushort4 ov;
    ov.x = f2bf(o[0]); ov.y = f2bf(o[1]); ov.z = f2bf(o[2]); ov.w = f2bf(o[3]);
    ((ushort4*)out_b)[i] = ov;
  }
}

// ---------------- launch ----------------
extern "C" void kernel_launch(void* const* d_in, const int* in_sizes, int n_in,
                              void* d_out, int out_size, void* d_ws, size_t ws_size,
                              hipStream_t stream) {
  const void* x    = d_in[0];
  const void* ei   = d_in[1];
  const void* W0    = d_in[3];
  const void* asrc0 = d_in[4];
  const void* adst0 = d_in[5];
  const void* b0    = d_in[6];
  const void* g0    = d_in[7];
  const void* be0   = d_in[8];
  const void* W1    = d_in[9];
  const void* asrc1 = d_in[10];
  const void* adst1 = d_in[11];
  const void* b1    = d_in[12];
  const void* g1    = d_in[13];
  const void* be1   = d_in[14];

  int N = in_sizes[0] / 64;
  int E = in_sizes[1] / 2;
  int NB = (N + 255) / 256;   // scan blocks
  int NG = (N + 63) / 64;     // gemm blocks

  char* p = (char*)d_ws;
  auto alloc = [&](size_t bytes) -> char* {
    char* r = p;
    p += (bytes + 255) & ~(size_t)255;
    return r;
  };
  int* flags    = (int*)alloc(256);
  int* deg      = (int*)alloc((size_t)N * 4);
  int* cursor   = (int*)alloc((size_t)N * 4);
  int* offsets  = (int*)alloc((size_t)(N + 1) * 4);
  int* blocksum = (int*)alloc((size_t)NB * 4);
  int* blockbase= (int*)alloc((size_t)(NB + 1) * 4);
  int* csr_src  = (int*)alloc((size_t)E * 4);
  unsigned short* WTx0 = (unsigned short*)alloc(272 * 64 * 2);
  unsigned short* WTx1 = (unsigned short*)alloc(272 * 64 * 2);
  unsigned short* xh = (unsigned short*)alloc((size_t)N * 256 * 2);
  float* als    = (float*)alloc((size_t)N * 4 * 4);
  float* ald    = (float*)alloc((size_t)N * 4 * 4);
  float* y      = (float*)alloc((size_t)N * 64 * 4);
  unsigned short* x2 = (unsigned short*)alloc((size_t)N * 64 * 2);
  float* gsum0  = (float*)alloc(256);
  float* gsq0   = (float*)alloc(256);
  float* gsum1  = (float*)alloc(256);
  float* gsq1   = (float*)alloc(256);

  hipMemsetAsync(deg, 0, (size_t)N * 4, stream);
  hipMemsetAsync(cursor, 0, (size_t)N * 4, stream);
  hipMemsetAsync(gsum0, 0, 1024, stream);

  detect_kernel<<<1, 256, 0, stream>>>((const unsigned short*)x, (const int*)ei, flags);
  wtrans_kernel<<<2, 256, 0, stream>>>(W0, asrc0, adst0, W1, asrc1, adst1, flags, 0, WTx0, WTx1);

  // CSR build (shared by both layers)
  hist_kernel<<<(E + 255) / 256, 256, 0, stream>>>(ei, E, N, flags, deg);
  partial_kernel<<<NB, 256, 0, stream>>>(deg, blocksum, N);
  scan_base_kernel<<<1, 64, 0, stream>>>(blocksum, blockbase, NB);
  scan_final_kernel<<<NB, 256, 0, stream>>>(deg, blockbase, offsets, N);
  scatter_kernel<<<(E + 255) / 256, 256, 0, stream>>>(ei, E, N, flags, offsets, cursor, csr_src);

  float* out_x = (float*)d_out;                    // output 0: final, fp32
  float* out_saved = out_x + (size_t)N * 64;       // output 1: layer-2 pre-BN, fp32

  // ---- layer 0 ----
  gemm_mfma<<<NG, 256, 0, stream>>>(x, WTx0, flags, 1, xh, als, ald, N);
  agg_kernel<<<(N + 3) / 4, 256, 0, stream>>>(xh, als, ald, offsets, csr_src, b0, flags, y,
                                              (float*)nullptr, N);
  stats_kernel<<<250, 256, 0, stream>>>(y, gsum0, gsq0, N);
  bn_kernel<<<(N * 16 + 255) / 256, 256, 0, stream>>>(y, gsum0, gsq0, g0, be0, flags,
                                                      (float*)nullptr, x2, N);

  // ---- layer 1 ----
  gemm_mfma<<<NG, 256, 0, stream>>>(x2, WTx1, flags, 0, xh, als, ald, N);
  agg_kernel<<<(N + 3) / 4, 256, 0, stream>>>(xh, als, ald, offsets, csr_src, b1, flags, y,
                                              out_saved, N);
  stats_kernel<<<250, 256, 0, stream>>>(y, gsum1, gsq1, N);
  bn_kernel<<<(N * 16 + 255) / 256, 256, 0, stream>>>(y, gsum1, gsq1, g1, be1, flags,
                                                      out_x, (unsigned short*)nullptr, N);
}